// Round 3
// baseline (615.740 us; speedup 1.0000x reference)
//
#include <hip/hip_runtime.h>
#include <math.h>

// ListwiseSmoothINDCGKLoss: bs x ll (16384 x 2048) fp32 scores + graded labels
// -> scalar sum(1 - ndcg@10).
// One 512-thread block (8 waves) per row, EPT=4 elems/thread so the full live
// set (s2[4], lv[4], prod[4], ex[4] + scalars ~= 36 floats) fits the compiler's
// 64-VGPR / 8-waves-per-SIMD envelope -> NO scratch spills (round-2 failure
// mode: EPT=8 -> 900 MB of spill traffic dominated runtime).
// Key ideas:
//  - softmax scale-invariance: rel = sle/se and approx = ex/se need only an
//    upper bound M in [truemax, truemax+~118]. Row-min of s2 is exactly 0 so
//    truemax >= 0; |prod_k| <= 0.9^k, so M_k = min(s2max*0.9^k, 118) is safe
//    -> NO per-k max reduction.
//  - one barrier per k (ping-pong LDS), ds_swizzle xor-reduce.
//  - no divides: rcp + reciprocal-denominator constants.
//  - IDCG via packed label histogram + closed form (labels are ints 0..4).

constexpr int LL      = 2048;
constexpr int THREADS = 512;          // 8 waves
constexpr int EPT     = LL / THREADS; // 4
constexpr int NHALF   = THREADS / 32; // 16 half-waves
constexpr int KTOP    = 10;
constexpr float ALPHA  = 10.0f;
constexpr float EPSF   = 1e-10f;
constexpr float LOG2E  = 1.44269504088896340736f;
constexpr float MCLAMP = 118.0f;

// 1 / log2(k+2), k = 0..9
__device__ constexpr float INVDEN[KTOP] = {
    1.0f,                0.6309297535714574f, 0.5f,                0.43067655807339306f,
    0.38685280723454163f,0.356207187108022f,  0.3333333333333333f, 0.31546487678572877f,
    0.30102999566398114f,0.2890648263178878f};

template <int PAT>
__device__ __forceinline__ float swzf(float v) {
    return __int_as_float(__builtin_amdgcn_ds_swizzle(__float_as_int(v), PAT));
}
template <int PAT>
__device__ __forceinline__ int swzi(int v) {
    return __builtin_amdgcn_ds_swizzle(v, PAT);
}

// reduce within each 32-lane half (xor 1,2,4,8,16)
__device__ __forceinline__ void half_sum2(float& a, float& b) {
    a += swzf<0x041F>(a); b += swzf<0x041F>(b);
    a += swzf<0x081F>(a); b += swzf<0x081F>(b);
    a += swzf<0x101F>(a); b += swzf<0x101F>(b);
    a += swzf<0x201F>(a); b += swzf<0x201F>(b);
    a += swzf<0x401F>(a); b += swzf<0x401F>(b);
}
__device__ __forceinline__ void half_minmax(float& mn, float& mx) {
    mn = fminf(mn, swzf<0x041F>(mn)); mx = fmaxf(mx, swzf<0x041F>(mx));
    mn = fminf(mn, swzf<0x081F>(mn)); mx = fmaxf(mx, swzf<0x081F>(mx));
    mn = fminf(mn, swzf<0x101F>(mn)); mx = fmaxf(mx, swzf<0x101F>(mx));
    mn = fminf(mn, swzf<0x201F>(mn)); mx = fmaxf(mx, swzf<0x201F>(mx));
    mn = fminf(mn, swzf<0x401F>(mn)); mx = fmaxf(mx, swzf<0x401F>(mx));
}
__device__ __forceinline__ void half_isum3(int& a, int& b, int& c) {
    a += swzi<0x041F>(a); b += swzi<0x041F>(b); c += swzi<0x041F>(c);
    a += swzi<0x081F>(a); b += swzi<0x081F>(b); c += swzi<0x081F>(c);
    a += swzi<0x101F>(a); b += swzi<0x101F>(b); c += swzi<0x101F>(c);
    a += swzi<0x201F>(a); b += swzi<0x201F>(b); c += swzi<0x201F>(c);
    a += swzi<0x401F>(a); b += swzi<0x401F>(b); c += swzi<0x401F>(c);
}

__global__ __launch_bounds__(THREADS) void ndcg_loss_kernel(
    const float* __restrict__ s, const float* __restrict__ label,
    float* __restrict__ ws, float* __restrict__ out, int mode) {
    __shared__ __align__(16) float red[2][2 * NHALF];  // ping-pong: 16 halves x float2
    __shared__ int ibuf[3 * NHALF];                    // 16 halves x 3 packed counts

    const int    tid  = threadIdx.x;
    const size_t row  = blockIdx.x;
    const int    half = tid >> 5;  // 0..15

    float4 a = ((const float4*)(s + row * (size_t)LL))[tid];
    float4 b = ((const float4*)(label + row * (size_t)LL))[tid];
    float  sv[EPT] = {a.x, a.y, a.z, a.w};
    float  lv[EPT] = {b.x, b.y, b.z, b.w};

    // ---- row min & max of s (one block reduction, once) ----
    float mn = sv[0], mx = sv[0];
#pragma unroll
    for (int j = 1; j < EPT; ++j) { mn = fminf(mn, sv[j]); mx = fmaxf(mx, sv[j]); }
    half_minmax(mn, mx);
    if ((tid & 31) == 0) ((float2*)red[0])[half] = make_float2(mn, mx);
    __syncthreads();
    {
        const float4* r = (const float4*)red[0];
#pragma unroll
        for (int q = 0; q < 8; ++q) {
            float4 v = r[q];
            mn = fminf(mn, fminf(v.x, v.z));
            mx = fmaxf(mx, fmaxf(v.y, v.w));
        }
    }

    float s2[EPT];
#pragma unroll
    for (int j = 0; j < EPT; ++j) s2[j] = (sv[j] - mn) * (ALPHA * LOG2E);
    float M = fminf((mx - mn) * (ALPHA * LOG2E), MCLAMP);

    // ---- label histogram (exact ints 0..4) -> packed counts -> IDCG ----
    int c0 = 0, c1 = 0, c2 = 0, c3 = 0, c4 = 0;
#pragma unroll
    for (int j = 0; j < EPT; ++j) {
        c0 += (lv[j] == 0.0f); c1 += (lv[j] == 1.0f); c2 += (lv[j] == 2.0f);
        c3 += (lv[j] == 3.0f); c4 += (lv[j] == 4.0f);
    }
    int A = c0 | (c1 << 16), B = c2 | (c3 << 16), C = c4;
    half_isum3(A, B, C);  // fields <= 32*4 = 128, no overflow
    if ((tid & 31) == 0) {
        ibuf[half * 3] = A; ibuf[half * 3 + 1] = B; ibuf[half * 3 + 2] = C;
    }
    __syncthreads();  // also orders red[0] reads above vs k=0 writes below
    A = 0; B = 0; C = 0;
#pragma unroll
    for (int h = 0; h < NHALF; ++h) {
        A += ibuf[h * 3]; B += ibuf[h * 3 + 1]; C += ibuf[h * 3 + 2];
    }
    const int n4 = C, n3 = n4 + (B >> 16), n2 = n3 + (B & 0xFFFF), n1 = n2 + (A >> 16);
    float idcg = EPSF;
#pragma unroll
    for (int slot = 0; slot < KTOP; ++slot) {
        int v = (slot < n4) + (slot < n3) + (slot < n2) + (slot < n1);
        idcg = fmaf((float)(1 << v), INVDEN[slot], idcg);
    }

    // ---- K sequential scale-invariant softmax passes ----
    float prod[EPT];
#pragma unroll
    for (int j = 0; j < EPT; ++j) prod[j] = 1.0f;
    float dcg = EPSF;

#pragma unroll
    for (int k = 0; k < KTOP; ++k) {
        float ex[EPT];
        float se = 0.0f, sle = 0.0f;
#pragma unroll
        for (int j = 0; j < EPT; ++j) {
            float x = __builtin_amdgcn_exp2f(fmaf(s2[j], prod[j], -M));
            ex[j] = x;
            se += x;
            sle = fmaf(lv[j], x, sle);
        }
        half_sum2(se, sle);
        if ((tid & 31) == 0) ((float2*)red[k & 1])[half] = make_float2(se, sle);
        __syncthreads();
        {
            const float4* r = (const float4*)red[k & 1];
            se = 0.0f; sle = 0.0f;
#pragma unroll
            for (int q = 0; q < 8; ++q) {
                float4 v = r[q];
                se  += v.x + v.z;
                sle += v.y + v.w;
            }
        }

        float inv = __builtin_amdgcn_rcpf(se);
        dcg = fmaf(__builtin_amdgcn_exp2f(sle * inv), INVDEN[k], dcg);
#pragma unroll
        for (int j = 0; j < EPT; ++j) prod[j] *= fmaf(ex[j], -inv, 0.9f);
        M *= 0.9f;
    }

    if (tid == 0) {
        float loss = 1.0f - dcg / idcg;
        if (mode) atomicAdd(out, loss);
        else      ws[row] = loss;
    }
}

__global__ __launch_bounds__(256) void reduce_sum_kernel(
    const float* __restrict__ w, float* __restrict__ out, int n4) {
    __shared__ float sb[8];
    float acc = 0.0f;
    const float4* w4 = (const float4*)w;
    for (int i = threadIdx.x; i < n4; i += 256) {
        float4 q = w4[i];
        acc += (q.x + q.y) + (q.z + q.w);
    }
    float a = acc;
    a += swzf<0x041F>(a); a += swzf<0x081F>(a); a += swzf<0x101F>(a);
    a += swzf<0x201F>(a); a += swzf<0x401F>(a);
    if ((threadIdx.x & 31) == 0) sb[threadIdx.x >> 5] = a;
    __syncthreads();
    if (threadIdx.x == 0) {
        float t = 0.0f;
#pragma unroll
        for (int i = 0; i < 8; ++i) t += sb[i];
        out[0] = t;
    }
}

__global__ void zero_out_kernel(float* out) { out[0] = 0.0f; }

extern "C" void kernel_launch(void* const* d_in, const int* in_sizes, int n_in,
                              void* d_out, int out_size, void* d_ws,
                              size_t ws_size, hipStream_t stream) {
    const float* s     = (const float*)d_in[0];
    const float* label = (const float*)d_in[1];
    float*       out   = (float*)d_out;
    const int    bs    = in_sizes[0] / LL;

    if (ws_size >= (size_t)bs * sizeof(float)) {
        float* w = (float*)d_ws;
        ndcg_loss_kernel<<<bs, THREADS, 0, stream>>>(s, label, w, nullptr, 0);
        reduce_sum_kernel<<<1, 256, 0, stream>>>(w, out, bs / 4);
    } else {
        zero_out_kernel<<<1, 1, 0, stream>>>(out);
        ndcg_loss_kernel<<<bs, THREADS, 0, stream>>>(s, label, nullptr, out, 1);
    }
}

// Round 4
// 164.341 us; speedup vs baseline: 3.7467x; 3.7467x over previous
//
#include <hip/hip_runtime.h>
#include <math.h>

// ListwiseSmoothINDCGKLoss: bs x ll (16384 x 2048) fp32 scores + graded labels
// -> scalar sum(1 - ndcg@10).
//
// Structure: one 256-thread block (4 waves) per row, 8 elems/thread.
// CRITICAL LESSON (rounds 2-3): small per-thread local arrays (float x[8])
// were materialized as scratch allocas (NOT VGPR-pressure spills: round 3 had
// VGPR=128, live set ~35, yet wrote 1.5 GB of scratch to HBM at 185 B/thread).
// Fix: NO local arrays at all -- every per-element value is a named scalar,
// 8-fold expanded. Only LDS and compile-time-folded constexpr tables remain.
//
// Algorithmic structure (validated rounds 2-3, absmax == 0):
//  - softmax scale-invariance: rel = sle/se and approx = e/se only need a
//    bound M in [truemax, truemax+~118]. Row-min of z is exactly 0 so
//    truemax >= 0; |prod_k| <= 0.9^k, so M_k = min(range,118)*0.9^k is safe
//    -> NO per-k max reduction.
//  - one barrier per k (ping-pong LDS float2), __shfl_xor wave reduction.
//  - no divides in the k-loop: v_rcp + reciprocal-log2 constants.
//  - IDCG via packed label histogram + closed form (labels are ints 0..4).

constexpr int LL      = 2048;
constexpr int THREADS = 256;  // 4 waves
constexpr int KTOP    = 10;
constexpr float ALPHA  = 10.0f;
constexpr float EPSF   = 1e-10f;
constexpr float LOG2E  = 1.44269504088896340736f;
constexpr float MCLAMP = 118.0f;

// 1 / log2(k+2), k = 0..9 -- constexpr + unroll-constant index => folds to
// immediates, no memory access.
__device__ constexpr float INVDEN[KTOP] = {
    1.0f,                 0.6309297535714574f, 0.5f,                0.43067655807339306f,
    0.38685280723454163f, 0.356207187108022f,  0.3333333333333333f, 0.31546487678572877f,
    0.30102999566398114f, 0.2890648263178878f};

__global__ __launch_bounds__(THREADS) void ndcg_loss_kernel(
    const float* __restrict__ s, const float* __restrict__ label,
    float* __restrict__ ws, float* __restrict__ out, int mode) {
    __shared__ float2 smr[2][4];  // ping-pong (se,sle) per wave
    __shared__ float2 smm[4];     // (min,max) per wave
    __shared__ int    smh[12];    // packed hist per wave: A,B,C x 4

    const int    tid  = threadIdx.x;
    const int    wave = tid >> 6;
    const int    lane = tid & 63;
    const size_t row  = blockIdx.x;

    const float4* sp = (const float4*)(s + row * (size_t)LL);
    const float4* lp = (const float4*)(label + row * (size_t)LL);
    const float4  A0 = sp[tid * 2], A1 = sp[tid * 2 + 1];
    const float4  B0 = lp[tid * 2], B1 = lp[tid * 2 + 1];

    // labels as named scalars
    const float q0 = B0.x, q1 = B0.y, q2 = B0.z, q3 = B0.w;
    const float q4 = B1.x, q5 = B1.y, q6 = B1.z, q7 = B1.w;

    // ---- row min/max of s ----
    float mn = fminf(fminf(fminf(A0.x, A0.y), fminf(A0.z, A0.w)),
                     fminf(fminf(A1.x, A1.y), fminf(A1.z, A1.w)));
    float mx = fmaxf(fmaxf(fmaxf(A0.x, A0.y), fmaxf(A0.z, A0.w)),
                     fmaxf(fmaxf(A1.x, A1.y), fmaxf(A1.z, A1.w)));
#pragma unroll
    for (int o = 32; o; o >>= 1) {
        mn = fminf(mn, __shfl_xor(mn, o, 64));
        mx = fmaxf(mx, __shfl_xor(mx, o, 64));
    }

    // ---- packed label histogram: A = c0|c1<<16, B = c2|c3<<16, C = c4 ----
    int cA = 0, cB = 0, cC = 0;
    {
        auto acc = [&](float lv) {
            const int li = (int)lv;
            cA += (li == 0) + ((li == 1) << 16);
            cB += (li == 2) + ((li == 3) << 16);
            cC += (li == 4);
        };
        acc(q0); acc(q1); acc(q2); acc(q3); acc(q4); acc(q5); acc(q6); acc(q7);
    }
#pragma unroll
    for (int o = 32; o; o >>= 1) {
        cA += __shfl_xor(cA, o, 64);
        cB += __shfl_xor(cB, o, 64);
        cC += __shfl_xor(cC, o, 64);
    }
    if (lane == 0) {
        smm[wave] = make_float2(mn, mx);
        smh[wave * 3] = cA; smh[wave * 3 + 1] = cB; smh[wave * 3 + 2] = cC;
    }
    __syncthreads();
    mn = fminf(fminf(smm[0].x, smm[1].x), fminf(smm[2].x, smm[3].x));
    mx = fmaxf(fmaxf(smm[0].y, smm[1].y), fmaxf(smm[2].y, smm[3].y));
    cA = ((smh[0] + smh[3]) + (smh[6] + smh[9]));
    cB = ((smh[1] + smh[4]) + (smh[7] + smh[10]));
    cC = ((smh[2] + smh[5]) + (smh[8] + smh[11]));

    const int n4 = cC;
    const int n3 = n4 + (cB >> 16);
    const int n2 = n3 + (cB & 0xFFFF);
    const int n1 = n2 + (cA >> 16);
    float idcg = EPSF;
#pragma unroll
    for (int slot = 0; slot < KTOP; ++slot) {
        const int v = (slot < n4) + (slot < n3) + (slot < n2) + (slot < n1);
        idcg = fmaf((float)(1 << v), INVDEN[slot], idcg);
    }

    // ---- shifted, log2-scaled scores as named scalars ----
    const float Cc = ALPHA * LOG2E;
    const float z0 = (A0.x - mn) * Cc, z1 = (A0.y - mn) * Cc;
    const float z2 = (A0.z - mn) * Cc, z3 = (A0.w - mn) * Cc;
    const float z4 = (A1.x - mn) * Cc, z5 = (A1.y - mn) * Cc;
    const float z6 = (A1.z - mn) * Cc, z7 = (A1.w - mn) * Cc;
    float M = fminf((mx - mn) * Cc, MCLAMP);

    float p0 = 1.0f, p1 = 1.0f, p2 = 1.0f, p3 = 1.0f;
    float p4 = 1.0f, p5 = 1.0f, p6 = 1.0f, p7 = 1.0f;
    float dcg = EPSF;

#pragma unroll
    for (int k = 0; k < KTOP; ++k) {
        const float e0 = __builtin_amdgcn_exp2f(fmaf(z0, p0, -M));
        const float e1 = __builtin_amdgcn_exp2f(fmaf(z1, p1, -M));
        const float e2 = __builtin_amdgcn_exp2f(fmaf(z2, p2, -M));
        const float e3 = __builtin_amdgcn_exp2f(fmaf(z3, p3, -M));
        const float e4 = __builtin_amdgcn_exp2f(fmaf(z4, p4, -M));
        const float e5 = __builtin_amdgcn_exp2f(fmaf(z5, p5, -M));
        const float e6 = __builtin_amdgcn_exp2f(fmaf(z6, p6, -M));
        const float e7 = __builtin_amdgcn_exp2f(fmaf(z7, p7, -M));

        float se  = ((e0 + e1) + (e2 + e3)) + ((e4 + e5) + (e6 + e7));
        float sle = fmaf(q0, e0, q1 * e1) + fmaf(q2, e2, q3 * e3) +
                    fmaf(q4, e4, q5 * e5) + fmaf(q6, e6, q7 * e7);
#pragma unroll
        for (int o = 32; o; o >>= 1) {
            se  += __shfl_xor(se, o, 64);
            sle += __shfl_xor(sle, o, 64);
        }
        if (lane == 0) smr[k & 1][wave] = make_float2(se, sle);
        __syncthreads();
        {
            const float2 r0 = smr[k & 1][0], r1 = smr[k & 1][1];
            const float2 r2 = smr[k & 1][2], r3 = smr[k & 1][3];
            se  = (r0.x + r1.x) + (r2.x + r3.x);
            sle = (r0.y + r1.y) + (r2.y + r3.y);
        }

        const float inv = __builtin_amdgcn_rcpf(se);
        dcg = fmaf(__builtin_amdgcn_exp2f(sle * inv), INVDEN[k], dcg);

        p0 *= fmaf(e0, -inv, 0.9f); p1 *= fmaf(e1, -inv, 0.9f);
        p2 *= fmaf(e2, -inv, 0.9f); p3 *= fmaf(e3, -inv, 0.9f);
        p4 *= fmaf(e4, -inv, 0.9f); p5 *= fmaf(e5, -inv, 0.9f);
        p6 *= fmaf(e6, -inv, 0.9f); p7 *= fmaf(e7, -inv, 0.9f);
        M *= 0.9f;
    }

    if (tid == 0) {
        const float loss = 1.0f - dcg / idcg;
        if (mode) atomicAdd(out, loss);
        else      ws[row] = loss;
    }
}

__global__ __launch_bounds__(256) void reduce_sum_kernel(
    const float* __restrict__ w, float* __restrict__ out, int n4) {
    __shared__ float sb[4];
    float acc = 0.0f;
    const float4* w4 = (const float4*)w;
    for (int i = threadIdx.x; i < n4; i += 256) {
        const float4 v = w4[i];
        acc += (v.x + v.y) + (v.z + v.w);
    }
#pragma unroll
    for (int o = 32; o; o >>= 1) acc += __shfl_xor(acc, o, 64);
    if ((threadIdx.x & 63) == 0) sb[threadIdx.x >> 6] = acc;
    __syncthreads();
    if (threadIdx.x == 0) out[0] = (sb[0] + sb[1]) + (sb[2] + sb[3]);
}

__global__ void zero_out_kernel(float* out) { out[0] = 0.0f; }

extern "C" void kernel_launch(void* const* d_in, const int* in_sizes, int n_in,
                              void* d_out, int out_size, void* d_ws,
                              size_t ws_size, hipStream_t stream) {
    const float* s     = (const float*)d_in[0];
    const float* label = (const float*)d_in[1];
    float*       out   = (float*)d_out;
    const int    bs    = in_sizes[0] / LL;

    if (ws_size >= (size_t)bs * sizeof(float)) {
        float* w = (float*)d_ws;
        ndcg_loss_kernel<<<bs, THREADS, 0, stream>>>(s, label, w, nullptr, 0);
        reduce_sum_kernel<<<1, 256, 0, stream>>>(w, out, bs / 4);
    } else {
        zero_out_kernel<<<1, 1, 0, stream>>>(out);
        ndcg_loss_kernel<<<bs, THREADS, 0, stream>>>(s, label, nullptr, out, 1);
    }
}

// Round 5
// 89.695 us; speedup vs baseline: 6.8648x; 1.8322x over previous
//
#include <hip/hip_runtime.h>
#include <math.h>

// ListwiseSmoothINDCGKLoss: bs x ll (16384 x 2048) fp32 scores + graded labels
// -> scalar sum(1 - ndcg@10).
//
// Round-5 structure: ONE WAVE OWNS ONE ROW (EPT=32), 4 independent waves per
// 256-thread block -> zero __syncthreads, zero LDS. Per-k reduction is a
// 6-step DPP add (row_shr:1,2,4,8 + row_bcast:15,31 -> total in lane 63),
// pure VALU, then v_readlane broadcast. Register enabler: z is folded away --
// maintain w = z*prod directly (w' = w*(0.9 - e*inv)), saving 32 VGPRs.
//
// Carried lessons:
//  - NO local arrays (rounds 2-3: scratch allocas -> GBs of spill traffic);
//    every per-element value is a named scalar via macro expansion.
//  - scale-invariant softmax: exact row max not needed, M_k = min(range,118)*0.9^k
//    is a safe upper bound (row-min of z is 0, |prod|<=0.9^k). No per-k max.
//  - IDCG closed-form from packed label histogram (labels are ints 0..4).
//  - no divides in the loop: v_rcp + reciprocal-log2 constants.

constexpr int LL      = 2048;
constexpr int THREADS = 256;  // 4 waves; wave w handles row blockIdx*4+w
constexpr int RPB     = 4;
constexpr int KTOP    = 10;
constexpr float ALPHA  = 10.0f;
constexpr float EPSF   = 1e-10f;
constexpr float LOG2E  = 1.44269504088896340736f;
constexpr float MCLAMP = 118.0f;

// 1 / log2(k+2), k = 0..9 (constexpr + unroll-constant index => immediates)
__device__ constexpr float INVDEN[KTOP] = {
    1.0f,                 0.6309297535714574f, 0.5f,                0.43067655807339306f,
    0.38685280723454163f, 0.356207187108022f,  0.3333333333333333f, 0.31546487678572877f,
    0.30102999566398114f, 0.2890648263178878f};

// ---- DPP wave64 reductions (result lands in lane 63) ----
template <int CTRL>
__device__ __forceinline__ float dpp_addf(float v) {
    return v + __int_as_float(__builtin_amdgcn_update_dpp(
                   0, __float_as_int(v), CTRL, 0xF, 0xF, false));
}
template <int CTRL>
__device__ __forceinline__ float dpp_minf(float v) {
    return fminf(v, __int_as_float(__builtin_amdgcn_update_dpp(
                        0x7F800000, __float_as_int(v), CTRL, 0xF, 0xF, false)));
}
template <int CTRL>
__device__ __forceinline__ float dpp_maxf(float v) {
    return fmaxf(v, __int_as_float(__builtin_amdgcn_update_dpp(
                        (int)0xFF800000, __float_as_int(v), CTRL, 0xF, 0xF, false)));
}
template <int CTRL>
__device__ __forceinline__ int dpp_addi(int v) {
    return v + __builtin_amdgcn_update_dpp(0, v, CTRL, 0xF, 0xF, false);
}

// row_shr:1,2,4,8 then row_bcast:15, row_bcast:31
#define WAVE_RED(OP, v)                                                     \
    v = OP<0x111>(v); v = OP<0x112>(v); v = OP<0x114>(v); v = OP<0x118>(v); \
    v = OP<0x142>(v); v = OP<0x143>(v);

__device__ __forceinline__ float rl63f(float v) {
    return __int_as_float(__builtin_amdgcn_readlane(__float_as_int(v), 63));
}

// chunk expander: 8 chunks x 4 scalars = 32 elements per lane
#define CH(F) F(0) F(1) F(2) F(3) F(4) F(5) F(6) F(7)

__global__ __launch_bounds__(THREADS, 3) void ndcg_loss_kernel(
    const float* __restrict__ s, const float* __restrict__ label,
    float* __restrict__ ws, float* __restrict__ out, int mode) {
    const int    lane = threadIdx.x & 63;
    const int    wave = threadIdx.x >> 6;
    const size_t row  = (size_t)blockIdx.x * RPB + wave;

    const float4* sp = (const float4*)(s + row * (size_t)LL);
    const float4* lp = (const float4*)(label + row * (size_t)LL);

    // coalesced loads: chunk c = 1 KB contiguous (64 lanes x 16 B)
#define LOADS(c) const float4 sA##c = sp[(c) * 64 + lane];
    CH(LOADS)
#define LOADL(c) const float4 qA##c = lp[(c) * 64 + lane];
    CH(LOADL)

    // ---- row min / max ----
    float mn = sA0.x, mx = sA0.x;
#define MM(c)                                                                  \
    mn = fminf(mn, fminf(fminf(sA##c.x, sA##c.y), fminf(sA##c.z, sA##c.w)));   \
    mx = fmaxf(mx, fmaxf(fmaxf(sA##c.x, sA##c.y), fmaxf(sA##c.z, sA##c.w)));
    CH(MM)
    WAVE_RED(dpp_minf, mn)
    WAVE_RED(dpp_maxf, mx)
    mn = rl63f(mn);
    mx = rl63f(mx);

    // ---- packed label histogram: hA = c0|c1<<16, hB = c2|c3<<16, hC = c4 ----
    int hA = 0, hB = 0, hC = 0;
#define H1(q)                                   \
    {                                           \
        const int li = (int)(q);                \
        hA += (li == 0) + ((li == 1) << 16);    \
        hB += (li == 2) + ((li == 3) << 16);    \
        hC += (li == 4);                        \
    }
#define HC(c) H1(qA##c.x) H1(qA##c.y) H1(qA##c.z) H1(qA##c.w)
    CH(HC)
    WAVE_RED(dpp_addi, hA)
    WAVE_RED(dpp_addi, hB)
    WAVE_RED(dpp_addi, hC)
    hA = __builtin_amdgcn_readlane(hA, 63);
    hB = __builtin_amdgcn_readlane(hB, 63);
    hC = __builtin_amdgcn_readlane(hC, 63);

    const int n4 = hC;
    const int n3 = n4 + (hB >> 16);
    const int n2 = n3 + (hB & 0xFFFF);
    const int n1 = n2 + (hA >> 16);
    float idcg = EPSF;
#pragma unroll
    for (int slot = 0; slot < KTOP; ++slot) {
        const int v = (slot < n4) + (slot < n3) + (slot < n2) + (slot < n1);
        idcg = fmaf((float)(1 << v), INVDEN[slot], idcg);
    }

    // ---- w = z*prod, initialized to z = (s - mn)*ALPHA*log2(e) ----
    const float Cc = ALPHA * LOG2E;
#define WD(c)                                                        \
    float w##c##x = (sA##c.x - mn) * Cc, w##c##y = (sA##c.y - mn) * Cc, \
          w##c##z = (sA##c.z - mn) * Cc, w##c##w = (sA##c.w - mn) * Cc;
    CH(WD)
    float M   = fminf((mx - mn) * Cc, MCLAMP);
    float dcg = EPSF;

#pragma unroll
    for (int k = 0; k < KTOP; ++k) {
#define ED(c)                                                  \
    const float e##c##x = __builtin_amdgcn_exp2f(w##c##x - M), \
                e##c##y = __builtin_amdgcn_exp2f(w##c##y - M), \
                e##c##z = __builtin_amdgcn_exp2f(w##c##z - M), \
                e##c##w = __builtin_amdgcn_exp2f(w##c##w - M);
        CH(ED)
        float se = 0.0f, sle = 0.0f;
#define AC(c)                                                       \
    se += (e##c##x + e##c##y) + (e##c##z + e##c##w);                \
    sle += fmaf(qA##c.x, e##c##x, qA##c.y * e##c##y) +              \
           fmaf(qA##c.z, e##c##z, qA##c.w * e##c##w);
        CH(AC)
        WAVE_RED(dpp_addf, se)
        WAVE_RED(dpp_addf, sle)
        se  = rl63f(se);
        sle = rl63f(sle);

        const float inv = __builtin_amdgcn_rcpf(se);
        dcg = fmaf(__builtin_amdgcn_exp2f(sle * inv), INVDEN[k], dcg);

        // w' = w * (0.9 - e*inv)   [prod update folded into w]
#define UP(c)                                \
    w##c##x *= fmaf(e##c##x, -inv, 0.9f);    \
    w##c##y *= fmaf(e##c##y, -inv, 0.9f);    \
    w##c##z *= fmaf(e##c##z, -inv, 0.9f);    \
    w##c##w *= fmaf(e##c##w, -inv, 0.9f);
        CH(UP)
        M *= 0.9f;
    }

    if (lane == 0) {
        const float loss = 1.0f - dcg / idcg;
        if (mode) atomicAdd(out, loss);
        else      ws[row] = loss;
    }
}

__global__ __launch_bounds__(256) void reduce_sum_kernel(
    const float* __restrict__ w, float* __restrict__ out, int n4) {
    __shared__ float sb[4];
    float acc = 0.0f;
    const float4* w4 = (const float4*)w;
    for (int i = threadIdx.x; i < n4; i += 256) {
        const float4 v = w4[i];
        acc += (v.x + v.y) + (v.z + v.w);
    }
#pragma unroll
    for (int o = 32; o; o >>= 1) acc += __shfl_xor(acc, o, 64);
    if ((threadIdx.x & 63) == 0) sb[threadIdx.x >> 6] = acc;
    __syncthreads();
    if (threadIdx.x == 0) out[0] = (sb[0] + sb[1]) + (sb[2] + sb[3]);
}

__global__ void zero_out_kernel(float* out) { out[0] = 0.0f; }

extern "C" void kernel_launch(void* const* d_in, const int* in_sizes, int n_in,
                              void* d_out, int out_size, void* d_ws,
                              size_t ws_size, hipStream_t stream) {
    const float* s     = (const float*)d_in[0];
    const float* label = (const float*)d_in[1];
    float*       out   = (float*)d_out;
    const int    bs    = in_sizes[0] / LL;

    if ((bs % RPB) == 0 && ws_size >= (size_t)bs * sizeof(float)) {
        float* w = (float*)d_ws;
        ndcg_loss_kernel<<<bs / RPB, THREADS, 0, stream>>>(s, label, w, nullptr, 0);
        reduce_sum_kernel<<<1, 256, 0, stream>>>(w, out, bs / 4);
    } else {
        zero_out_kernel<<<1, 1, 0, stream>>>(out);
        ndcg_loss_kernel<<<bs / RPB, THREADS, 0, stream>>>(s, label, nullptr, out, 1);
    }
}